// Round 6
// baseline (219.287 us; speedup 1.0000x reference)
//
#include <hip/hip_runtime.h>
#include <math.h>

// Problem constants (from reference)
#define BB 16
#define NN 65536
#define DD 8
#define OUT_SIZE 4096
#define IN_SIZE 4096

#define BLOCKS_PER_B 64
#define NC (NN / BLOCKS_PER_B)        // 1024 tuples per block
#define BLOCK_THREADS 512             // 8 waves/block
#define ITERS (NC / BLOCK_THREADS)    // 2 tuples per thread

// y[b,o] = bias[o]  (output is re-poisoned before every timed launch)
__global__ void init_out(const float* __restrict__ bias, float* __restrict__ y) {
    int i = blockIdx.x * blockDim.x + threadIdx.x;     // 0 .. B*OUT_SIZE-1
    y[i] = bias[i & (OUT_SIZE - 1)];
}

// HW model established R0-R5: scatter time == LDS lane-atomics/CU x ~3.9 cy.
// (R2 vs R5: same count, chained vs distinct addresses -> identical time;
// R0/R1/R3/R4 at ~5.5 atomics/tuple all ~33-40 us; R2/R5 at 8 -> ~53 us.)
// ds_add_f32 retires ~1 lane / 4 cy serially; no counter shows it because
// the DS atomic unit has no util metric. Merged live-slot count (~5.5 =
// distinct oi per tuple) is at its floor, so round 6 routes HALF the
// atomic stream onto the idle L2 fp-atomic pipe: iteration 0 -> LDS ys,
// iteration 1 -> direct global unsafeAtomicAdd into y[b,:]. Waves are
// unsynchronized, so both units run concurrently at steady state.
// Everything else is the proven R4 structure (126.5 us):
//  - duplicate-oi merge (count reduction 8 -> ~5.5, proven +-15 us)
//  - LDS x-gathers (lgkmcnt domain, decoupled from streaming vmcnt)
//  - 4 blocks/CU (32 KB LDS, launch_bounds(512,8))
__global__ __launch_bounds__(BLOCK_THREADS, 8)
void hyper_scatter(const float* __restrict__ x,
                   const float* __restrict__ means,
                   const float* __restrict__ sigmas,
                   const float* __restrict__ values,
                   const float* __restrict__ noise,
                   float* __restrict__ y) {
    __shared__ float ys[OUT_SIZE];   // per-(b,chunk) partial output, 16 KB
    __shared__ float xs[IN_SIZE];    // staged x[b,:], 16 KB

    const int b     = blockIdx.x / BLOCKS_PER_B;
    const int chunk = blockIdx.x % BLOCKS_PER_B;
    const int tid   = threadIdx.x;
    const float* xb = x + (size_t)b * IN_SIZE;
    float* yb       = y + (size_t)b * OUT_SIZE;

    // zero partial accumulator + stage x[b] (512 threads, 2 float4 each)
    ((float4*)ys)[tid]                 = make_float4(0.f, 0.f, 0.f, 0.f);
    ((float4*)ys)[tid + BLOCK_THREADS] = make_float4(0.f, 0.f, 0.f, 0.f);
    ((float4*)xs)[tid]                 = ((const float4*)xb)[tid];
    ((float4*)xs)[tid + BLOCK_THREADS] = ((const float4*)xb)[tid + BLOCK_THREADS];
    __syncthreads();

    const size_t base0 = (size_t)b * NN + (size_t)(chunk * NC + tid);

    // ---- prefetch iteration 0 (7 loads, 80 B, all in flight together) ----
    float2 mean  = ((const float2*)means)[base0];
    float  sigma = sigmas[base0];
    float  value = values[base0];
    const float4* np4_0 = (const float4*)(noise + base0 * (size_t)(DD * 2));
    float4 nz0 = np4_0[0], nz1 = np4_0[1], nz2 = np4_0[2], nz3 = np4_0[3];

    #pragma unroll
    for (int it = 0; it < ITERS; ++it) {
        // rotate prefetched inputs into working registers
        const float2 m   = mean;
        const float  sg  = sigma;
        const float  val = value;
        const float4 c0 = nz0, c1 = nz1, c2 = nz2, c3 = nz3;

        // issue next iteration's streaming loads now; they drain at the
        // next rotation, a full tuple of compute away
        if (it + 1 < ITERS) {
            const size_t nb = base0 + (size_t)((it + 1) * BLOCK_THREADS);
            mean  = ((const float2*)means)[nb];
            sigma = sigmas[nb];
            value = values[nb];
            const float4* q4 = (const float4*)(noise + nb * (size_t)(DD * 2));
            nz0 = q4[0]; nz1 = q4[1]; nz2 = q4[2]; nz3 = q4[3];
        }

        const float nr[DD * 2] = {
            c0.x, c0.y, c0.z, c0.w,
            c1.x, c1.y, c1.z, c1.w,
            c2.x, c2.y, c2.z, c2.w,
            c3.x, c3.y, c3.z, c3.w };

        const float neg_inv_2s2 = -0.5f / (sg * sg);
        float p[DD];
        int   oi[DD], ii[DD];
        float psum = 0.f;
        #pragma unroll
        for (int d = 0; d < DD; ++d) {
            // EXACT sample rounding: mul-then-add, no FMA contraction,
            // so rintf() flips the same half-integer cases as np.round.
            float s0 = __fadd_rn(__fmul_rn(nr[2 * d],     sg), m.x);
            float s1 = __fadd_rn(__fmul_rn(nr[2 * d + 1], sg), m.y);
            float d0 = s0 - m.x;                // reference's diff (post-roundtrip)
            float d1 = s1 - m.y;
            float q  = d0 * d0 + d1 * d1;
            float pd = __expf(q * neg_inv_2s2); // 1/(2πσ²) cancels in normalization
            p[d] = pd;
            psum += pd;
            oi[d] = (int)fminf(fmaxf(rintf(s0), 0.f), (float)(OUT_SIZE - 1));
            ii[d] = (int)fminf(fmaxf(rintf(s1), 0.f), (float)(IN_SIZE - 1));
        }
        const float wscale = val / psum;        // one divide per tuple

        // ALL gathers from LDS (lgkmcnt domain, decoupled from streaming)
        float xv[DD];
        #pragma unroll
        for (int d = 0; d < DD; ++d)
            xv[d] = xs[ii[d]];

        float v[DD];
        #pragma unroll
        for (int d = 0; d < DD; ++d) v[d] = p[d] * xv[d];

        // merge duplicate oi within the 8 samples: 8 -> ~5.5 live slots
        // (atomic COUNT is the proven cost driver, ~3.9 cy per lane-atomic)
        bool deadO[DD];
        deadO[0] = false;
        #pragma unroll
        for (int d = 1; d < DD; ++d) {
            bool found = false;
            #pragma unroll
            for (int j = 0; j < d; ++j) {
                bool mch = (!deadO[j]) && (oi[j] == oi[d]);
                if (mch) v[j] += v[d];
                found = found || mch;
            }
            deadO[d] = found;
        }

        // PIPE SPLIT: iteration 0 -> DS atomic unit (ys), iteration 1 ->
        // L2 fp-atomic unit (y directly). Halves the per-CU DS lane-atomic
        // count; the two units run concurrently across unsynchronized waves.
        if ((it & 1) == 0) {
            #pragma unroll
            for (int d = 0; d < DD; ++d) {
                if (!deadO[d]) atomicAdd(&ys[oi[d]], wscale * v[d]);
            }
        } else {
            #pragma unroll
            for (int d = 0; d < DD; ++d) {
                if (!deadO[d]) unsafeAtomicAdd(&yb[oi[d]], wscale * v[d]);
            }
        }
    }
    __syncthreads();

    // one HW fp atomic per output element per block (coalesced, cheap)
    #pragma unroll
    for (int o = tid; o < OUT_SIZE; o += BLOCK_THREADS) {
        unsafeAtomicAdd(&yb[o], ys[o]);
    }
}

extern "C" void kernel_launch(void* const* d_in, const int* in_sizes, int n_in,
                              void* d_out, int out_size, void* d_ws, size_t ws_size,
                              hipStream_t stream) {
    const float* x      = (const float*)d_in[0];   // [B, IN_SIZE]
    const float* means  = (const float*)d_in[1];   // [B, N, 2]
    const float* sigmas = (const float*)d_in[2];   // [B, N]
    const float* values = (const float*)d_in[3];   // [B, N]
    const float* bias   = (const float*)d_in[4];   // [OUT_SIZE]
    const float* noise  = (const float*)d_in[5];   // [B, N, D, 2]
    float* y = (float*)d_out;                      // [B, OUT_SIZE]

    init_out<<<(BB * OUT_SIZE) / 256, 256, 0, stream>>>(bias, y);
    hyper_scatter<<<BB * BLOCKS_PER_B, BLOCK_THREADS, 0, stream>>>(
        x, means, sigmas, values, noise, y);
}